// Round 12
// baseline (9750.274 us; speedup 1.0000x reference)
//
#include <hip/hip_runtime.h>

#define Bn 64
#define Tn 2048
#define In 128
#define Hn 256
#define RS 512  // row stride in f16 elements for pre/out rows (1024 B)

#define H0S (Hn + 8)       // h0t row stride (f16 elems)
#define PLS (2 * Hn + 8)   // preL row stride (f16 elems)

typedef _Float16 h2 __attribute__((ext_vector_type(2)));
typedef _Float16 f16x8 __attribute__((ext_vector_type(8)));
typedef float f32x4 __attribute__((ext_vector_type(4)));

__device__ __forceinline__ float fast_sigmoid(float x) {
    return 1.0f / (1.0f + __expf(-x));
}
__device__ __forceinline__ float fast_tanh(float x) {
    return 2.0f / (1.0f + __expf(-2.0f * x)) - 1.0f;
}
__device__ __forceinline__ h2 bc2(float f) {
    return __builtin_bit_cast(h2, f);
}

#if __has_builtin(__builtin_amdgcn_fdot2)
__device__ __forceinline__ float dot2(h2 a, h2 b, float c) {
    return __builtin_amdgcn_fdot2(a, b, c, false);
}
#else
__device__ __forceinline__ float dot2(h2 a, h2 b, float c) {
    return c + (float)a.x * (float)b.x + (float)a.y * (float)b.y;
}
#endif

// ---------------------------------------------------------------------------
// K1: pre0[m][512] (f16, in d_out) = X[m][0:128] @ [Wih0 | Wax0] + [bh0 | ba0]
// ---------------------------------------------------------------------------
__global__ void gemm_x_kernel(const float* __restrict__ X,
                              const float* __restrict__ Wih0, const float* __restrict__ bh0,
                              const float* __restrict__ Wax0, const float* __restrict__ ba0,
                              _Float16* __restrict__ pre)
{
    __shared__ __align__(16) float Xs[64 * In];  // 32 KB
    const int m0 = blockIdx.x * 64;
    const int s  = blockIdx.y;
    const float* __restrict__ W    = s ? Wax0 : Wih0;
    const float* __restrict__ bias = s ? ba0  : bh0;

    {
        const float4* __restrict__ src = reinterpret_cast<const float4*>(X + (size_t)m0 * In);
        float4* __restrict__ dst = reinterpret_cast<float4*>(Xs);
        #pragma unroll
        for (int i = 0; i < 8; ++i) dst[threadIdx.x + 256 * i] = src[threadIdx.x + 256 * i];
    }
    __syncthreads();

    const int c  = threadIdx.x & 63;
    const int rg = threadIdx.x >> 6;
    const int mr = rg * 16;

    float acc[16][4];
    #pragma unroll
    for (int u = 0; u < 4; ++u) {
        const float bv = bias[c + 64 * u];
        #pragma unroll
        for (int r = 0; r < 16; ++r) acc[r][u] = bv;
    }

    const float4* __restrict__ Xs4 = reinterpret_cast<const float4*>(Xs);
    #pragma unroll 4
    for (int kc = 0; kc < 32; ++kc) {
        float wv[4][4];
        #pragma unroll
        for (int kk = 0; kk < 4; ++kk)
            #pragma unroll
            for (int u = 0; u < 4; ++u)
                wv[kk][u] = W[(size_t)(4 * kc + kk) * Hn + c + 64 * u];
        #pragma unroll
        for (int r = 0; r < 16; ++r) {
            const float4 xv = Xs4[(mr + r) * 32 + kc];
            #pragma unroll
            for (int u = 0; u < 4; ++u)
                acc[r][u] += xv.x * wv[0][u] + xv.y * wv[1][u] + xv.z * wv[2][u] + xv.w * wv[3][u];
        }
    }

    #pragma unroll
    for (int r = 0; r < 16; ++r)
        #pragma unroll
        for (int u = 0; u < 4; ++u)
            pre[(size_t)(m0 + mr + r) * RS + s * Hn + c + 64 * u] = (_Float16)acc[r][u];
}

// ---------------------------------------------------------------------------
// Fused two-layer scan with HYBRID step core (MFMA U-path || dot2 A-path).
//
// Wave roles (round-robin wave->SIMD => 2 MFMA + 2 dot2 waves per SIMD):
//   U-MFMA waves: w in {0-3, 8-11}; iu = w<4 ? w : w-4; kh=iu>>2, q=iu&3.
//     R3-verified fragment scheme, 16 MFMAs/wave/step. kh=1 publishes yU to
//     LDS; kh=0 (waves 0-3, col==tid) keeps its partial in-register.
//   A-dot2 waves: w in {4-7, 12-15}; 2-way K-split (64 h2 weight regs,
//     fits the 128-reg cap cleanly); kh=1 folds the pre-activation A term.
// Activation: tid<256, own-yU + LDS partials, 2 barriers/step (unchanged).
// Pipeline/fences: identical to R11 (group-amortized release/acquire).
// Consumer: preL reads HOISTED to chunk start (off the serial path).
// ---------------------------------------------------------------------------
__global__ __launch_bounds__(1024, 4)
void fused_scan(_Float16* __restrict__ pre,
                const float* __restrict__ WU0, const float* __restrict__ WA0,
                const float* __restrict__ Wih1, const float* __restrict__ Wax1,
                const float* __restrict__ bh1,  const float* __restrict__ ba1,
                const float* __restrict__ WU1,  const float* __restrict__ WA1,
                float* __restrict__ outf, float* __restrict__ hfin,
                int* __restrict__ prog)
{
    __shared__ __align__(16) _Float16 hbuf[2][Hn];    // 1 KB
    __shared__ __align__(16) float    ypU[Hn];        // 1 KB (U kh=1 partials)
    __shared__ __align__(16) float    apar[2][Hn];    // 2 KB (A partials)
    __shared__ __align__(16) _Float16 h0t[32][H0S];   // 16.9 KB
    __shared__ __align__(16) _Float16 preL[32][PLS];  // 33.3 KB

    const int tid  = threadIdx.x;
    const int lane = tid & 63;
    const int w    = tid >> 6;
    const int g    = lane >> 4;
    const int cl   = lane & 15;

    const bool isU = ((w >> 2) & 1) == 0;     // waves 0-3, 8-11
    const int  iu  = (w < 4) ? w : (w - 4);   // U index 0..7 (valid when isU)
    const int  khU = iu >> 2;
    const int  q   = iu & 3;
    const int  ia  = (w < 8) ? (w - 4) : (w - 8);  // A index 0..7 (when !isU)
    const int  aid = ia * 64 + lane;               // 0..511
    const int  colA = aid & 255;
    const int  khA  = aid >> 8;

    const int b = (blockIdx.x < Bn) ? blockIdx.x : (blockIdx.x - Bn);
    const int layer = (blockIdx.x < Bn) ? 0 : 1;

    const float* __restrict__ WU = layer ? WU1 : WU0;
    const float* __restrict__ WA = layer ? WA1 : WA0;

    // ---- U-side MFMA fragments (R3 scheme) ----
    f16x8 bfragU[4][4];   // [nt][kc]
    if (isU) {
        #pragma unroll
        for (int nt = 0; nt < 4; ++nt) {
            #pragma unroll
            for (int kc = 0; kc < 4; ++kc) {
                const int n  = 64 * q + 16 * nt + cl;
                const int k0 = 128 * khU + 32 * kc + 8 * g;
                f16x8 f;
                #pragma unroll
                for (int jj = 0; jj < 8; ++jj)
                    f[jj] = (_Float16)WU[(size_t)(k0 + jj) * Hn + n];
                bfragU[nt][kc] = f;
            }
        }
    }

    // ---- A-side dot2 weights: K rows [128*khA, +128) of column colA ----
    h2 bwA[64];
    if (!isU) {
        #pragma unroll
        for (int i = 0; i < 64; ++i) {
            const int k0 = 128 * khA + 2 * i;
            h2 a;
            a.x = (_Float16)WA[(size_t)k0 * Hn + colA];
            a.y = (_Float16)WA[(size_t)(k0 + 1) * Hn + colA];
            bwA[i] = a;
        }
    }

    _Float16* __restrict__ rowbase = pre + (size_t)b * Tn * RS;
    float hprev = 0.0f;   // live in tid<256

    if (layer == 0) {
        // ========================= layer 0 (producer) =========================
        if (tid < Hn) hbuf[0][tid] = (_Float16)0.0f;
        float pcU[8], pcA[8];
        if (tid < Hn) {
            #pragma unroll
            for (int k = 0; k < 8; ++k)
                pcU[k] = (float)rowbase[(size_t)k * RS + tid];
        }
        if (tid >= 768) {
            #pragma unroll
            for (int k = 0; k < 8; ++k)
                pcA[k] = (float)rowbase[(size_t)k * RS + Hn + (tid - 768)];
        }
        __syncthreads();

        for (int t0 = 0; t0 < Tn; t0 += 8) {
            float pnU[8], pnA[8];
            if (tid < Hn) {
                #pragma unroll
                for (int k = 0; k < 8; ++k) {
                    int tn = t0 + 8 + k;
                    if (tn > Tn - 1) tn = Tn - 1;
                    pnU[k] = (float)rowbase[(size_t)tn * RS + tid];
                }
            }
            if (tid >= 768) {
                #pragma unroll
                for (int k = 0; k < 8; ++k) {
                    int tn = t0 + 8 + k;
                    if (tn > Tn - 1) tn = Tn - 1;
                    pnA[k] = (float)rowbase[(size_t)tn * RS + Hn + (tid - 768)];
                }
            }

            float hst[8];

            #pragma unroll
            for (int ph = 0; ph < 8; ++ph) {
                const int t = t0 + ph;
                float yv = 0.0f;

                if (isU) {
                    const float4* __restrict__ hb4 =
                        reinterpret_cast<const float4*>(&hbuf[t & 1][128 * khU]);
                    f16x8 af[4];
                    #pragma unroll
                    for (int kc = 0; kc < 4; ++kc)
                        af[kc] = __builtin_bit_cast(f16x8, hb4[4 * kc + g]);

                    const f32x4 z = {0.0f, 0.0f, 0.0f, 0.0f};
                    f32x4 a0 = __builtin_amdgcn_mfma_f32_16x16x32_f16(af[0], bfragU[0][0], z, 0, 0, 0);
                    f32x4 a1 = __builtin_amdgcn_mfma_f32_16x16x32_f16(af[0], bfragU[1][0], z, 0, 0, 0);
                    f32x4 a2 = __builtin_amdgcn_mfma_f32_16x16x32_f16(af[0], bfragU[2][0], z, 0, 0, 0);
                    f32x4 a3 = __builtin_amdgcn_mfma_f32_16x16x32_f16(af[0], bfragU[3][0], z, 0, 0, 0);
                    #pragma unroll
                    for (int kc = 1; kc < 4; ++kc) {
                        a0 = __builtin_amdgcn_mfma_f32_16x16x32_f16(af[kc], bfragU[0][kc], a0, 0, 0, 0);
                        a1 = __builtin_amdgcn_mfma_f32_16x16x32_f16(af[kc], bfragU[1][kc], a1, 0, 0, 0);
                        a2 = __builtin_amdgcn_mfma_f32_16x16x32_f16(af[kc], bfragU[2][kc], a2, 0, 0, 0);
                        a3 = __builtin_amdgcn_mfma_f32_16x16x32_f16(af[kc], bfragU[3][kc], a3, 0, 0, 0);
                    }
                    const float y01 = (lane & 16) ? a1.x : a0.x;
                    const float y23 = (lane & 16) ? a3.x : a2.x;
                    yv = (lane & 32) ? y23 : y01;
                    if (khU) ypU[64 * q + lane] = yv;
                } else {
                    const f16x8* __restrict__ hbA =
                        reinterpret_cast<const f16x8*>(&hbuf[t & 1][128 * khA]);
                    float c0 = 0.0f, c1 = 0.0f, c2 = 0.0f, c3 = 0.0f;
                    #pragma unroll
                    for (int r = 0; r < 16; ++r) {
                        const f16x8 v = hbA[r];
                        const h2 p0 = __builtin_shufflevector(v, v, 0, 1);
                        const h2 p1 = __builtin_shufflevector(v, v, 2, 3);
                        const h2 p2 = __builtin_shufflevector(v, v, 4, 5);
                        const h2 p3 = __builtin_shufflevector(v, v, 6, 7);
                        c0 = dot2(p0, bwA[4 * r + 0], c0);
                        c1 = dot2(p1, bwA[4 * r + 1], c1);
                        c2 = dot2(p2, bwA[4 * r + 2], c2);
                        c3 = dot2(p3, bwA[4 * r + 3], c3);
                    }
                    float part = (c0 + c1) + (c2 + c3);
                    if (khA) part += pcA[ph];
                    apar[khA][colA] = part;
                }
                __syncthreads();   // partials ready; hbuf reads done

                if (tid < Hn) {
                    const float yU = yv + ypU[tid] + pcU[ph];
                    const float yA = apar[0][tid] + apar[1][tid];
                    const float cand  = fast_tanh(yU);
                    const float alpha = fast_sigmoid(yA);
                    const float hn = hprev + alpha * (cand - hprev);
                    hprev = hn;
                    hst[ph] = hn;
                    hbuf[(t + 1) & 1][tid] = (_Float16)hn;
                }
                __syncthreads();   // hbuf[(t+1)&1] ready; partial buffers free
            }

            // chunk flush: h0 rows -> global (f16, U-half of pre0 rows)
            if (tid < Hn) {
                #pragma unroll
                for (int k = 0; k < 8; ++k)
                    rowbase[(size_t)(t0 + k) * RS + tid] = (_Float16)hst[k];
                #pragma unroll
                for (int k = 0; k < 8; ++k) pcU[k] = pnU[k];
            }
            if (tid >= 768) {
                #pragma unroll
                for (int k = 0; k < 8; ++k) pcA[k] = pnA[k];
            }

            // group boundary: drain stores, ONE fence, release
            if (((t0 >> 3) & 3) == 3) {
                __syncthreads();
                if (tid == 0) {
                    __threadfence();
                    __hip_atomic_store(prog + b, (t0 >> 5) + 1,
                                       __ATOMIC_RELEASE, __HIP_MEMORY_SCOPE_AGENT);
                }
            }
        }

        if (tid < Hn) hfin[b * Hn + tid] = hprev;

    } else {
        // ========================= layer 1 (consumer) =========================
        // mini-GEMM B fragments (persistent; touched once per group)
        f16x8 bfr0[8], bfr1[8];
        float biasv0, biasv1;
        int cg0, cg1;
        {
            const int ntgA = 2 * w, ntgB = 2 * w + 1;
            const float* __restrict__ WmA = (ntgA < 16) ? Wih1 : Wax1;
            const float* __restrict__ WmB = (ntgB < 16) ? Wih1 : Wax1;
            const int nA = 16 * (ntgA & 15) + cl;
            const int nB = 16 * (ntgB & 15) + cl;
            biasv0 = (ntgA < 16) ? bh1[nA] : ba1[nA];
            biasv1 = (ntgB < 16) ? bh1[nB] : ba1[nB];
            cg0 = (ntgA < 16) ? nA : (Hn + nA);
            cg1 = (ntgB < 16) ? nB : (Hn + nB);
            #pragma unroll
            for (int kc = 0; kc < 8; ++kc) {
                const int k0 = 32 * kc + 8 * g;
                f16x8 fa, fb;
                #pragma unroll
                for (int jj = 0; jj < 8; ++jj) {
                    fa[jj] = (_Float16)WmA[(size_t)(k0 + jj) * Hn + nA];
                    fb[jj] = (_Float16)WmB[(size_t)(k0 + jj) * Hn + nB];
                }
                bfr0[kc] = fa;
                bfr1[kc] = fb;
            }
        }

        float* __restrict__ outb = outf + (size_t)b * Tn * Hn;

        if (tid < Hn) hbuf[0][tid] = (_Float16)0.0f;
        __syncthreads();

        for (int grp = 0; grp < Tn / 32; ++grp) {
            const int t0g = 32 * grp;

            if (tid == 0) {
                while (__hip_atomic_load(prog + b, __ATOMIC_RELAXED,
                                         __HIP_MEMORY_SCOPE_AGENT) <= grp)
                    __builtin_amdgcn_s_sleep(8);
                (void)__hip_atomic_load(prog + b, __ATOMIC_ACQUIRE,
                                        __HIP_MEMORY_SCOPE_AGENT);
            }
            __syncthreads();

            // 32 h0 rows -> LDS
            #pragma unroll
            for (int qq = 0; qq < 4; ++qq) {
                const int id  = tid + 1024 * qq;
                const int r   = id >> 7;
                const int off = id & 127;
                const unsigned int v = *reinterpret_cast<const unsigned int*>(
                    rowbase + (size_t)(t0g + r) * RS + 2 * off);
                *reinterpret_cast<unsigned int*>(&h0t[r][2 * off]) = v;
            }
            __syncthreads();

            // M=32 mini-GEMM -> preL
            #pragma unroll
            for (int mt = 0; mt < 2; ++mt) {
                f16x8 af[8];
                #pragma unroll
                for (int kc = 0; kc < 8; ++kc)
                    af[kc] = *reinterpret_cast<const f16x8*>(
                        &h0t[16 * mt + cl][32 * kc + 8 * g]);

                const f32x4 z = {0.0f, 0.0f, 0.0f, 0.0f};
                f32x4 a0 = __builtin_amdgcn_mfma_f32_16x16x32_f16(af[0], bfr0[0], z, 0, 0, 0);
                f32x4 a1 = __builtin_amdgcn_mfma_f32_16x16x32_f16(af[0], bfr1[0], z, 0, 0, 0);
                #pragma unroll
                for (int kc = 1; kc < 8; ++kc) {
                    a0 = __builtin_amdgcn_mfma_f32_16x16x32_f16(af[kc], bfr0[kc], a0, 0, 0, 0);
                    a1 = __builtin_amdgcn_mfma_f32_16x16x32_f16(af[kc], bfr1[kc], a1, 0, 0, 0);
                }
                const int r0 = 16 * mt + (lane >> 4) * 4;
                #pragma unroll
                for (int ri = 0; ri < 4; ++ri) {
                    preL[r0 + ri][cg0] = (_Float16)(a0[ri] + biasv0);
                    preL[r0 + ri][cg1] = (_Float16)(a1[ri] + biasv1);
                }
            }
            __syncthreads();

            for (int cc = 0; cc < 4; ++cc) {
                const int t0 = t0g + 8 * cc;

                // HOISTED pre reads (off the serial activation path)
                float pcU[8], pcA[8];
                if (tid < Hn) {
                    #pragma unroll
                    for (int ph = 0; ph < 8; ++ph)
                        pcU[ph] = (float)preL[8 * cc + ph][tid];
                }
                if (tid >= 768) {
                    #pragma unroll
                    for (int ph = 0; ph < 8; ++ph)
                        pcA[ph] = (float)preL[8 * cc + ph][Hn + (tid - 768)];
                }

                float hst[8];
                #pragma unroll
                for (int ph = 0; ph < 8; ++ph) {
                    const int t = t0 + ph;
                    float yv = 0.0f;

                    if (isU) {
                        const float4* __restrict__ hb4 =
                            reinterpret_cast<const float4*>(&hbuf[t & 1][128 * khU]);
                        f16x8 af[4];
                        #pragma unroll
                        for (int kc = 0; kc < 4; ++kc)
                            af[kc] = __builtin_bit_cast(f16x8, hb4[4 * kc + g]);

                        const f32x4 z = {0.0f, 0.0f, 0.0f, 0.0f};
                        f32x4 a0 = __builtin_amdgcn_mfma_f32_16x16x32_f16(af[0], bfragU[0][0], z, 0, 0, 0);
                        f32x4 a1 = __builtin_amdgcn_mfma_f32_16x16x32_f16(af[0], bfragU[1][0], z, 0, 0, 0);
                        f32x4 a2 = __builtin_amdgcn_mfma_f32_16x16x32_f16(af[0], bfragU[2][0], z, 0, 0, 0);
                        f32x4 a3 = __builtin_amdgcn_mfma_f32_16x16x32_f16(af[0], bfragU[3][0], z, 0, 0, 0);
                        #pragma unroll
                        for (int kc = 1; kc < 4; ++kc) {
                            a0 = __builtin_amdgcn_mfma_f32_16x16x32_f16(af[kc], bfragU[0][kc], a0, 0, 0, 0);
                            a1 = __builtin_amdgcn_mfma_f32_16x16x32_f16(af[kc], bfragU[1][kc], a1, 0, 0, 0);
                            a2 = __builtin_amdgcn_mfma_f32_16x16x32_f16(af[kc], bfragU[2][kc], a2, 0, 0, 0);
                            a3 = __builtin_amdgcn_mfma_f32_16x16x32_f16(af[kc], bfragU[3][kc], a3, 0, 0, 0);
                        }
                        const float y01 = (lane & 16) ? a1.x : a0.x;
                        const float y23 = (lane & 16) ? a3.x : a2.x;
                        yv = (lane & 32) ? y23 : y01;
                        if (khU) ypU[64 * q + lane] = yv;
                    } else {
                        const f16x8* __restrict__ hbA =
                            reinterpret_cast<const f16x8*>(&hbuf[t & 1][128 * khA]);
                        float c0 = 0.0f, c1 = 0.0f, c2 = 0.0f, c3 = 0.0f;
                        #pragma unroll
                        for (int r = 0; r < 16; ++r) {
                            const f16x8 v = hbA[r];
                            const h2 p0 = __builtin_shufflevector(v, v, 0, 1);
                            const h2 p1 = __builtin_shufflevector(v, v, 2, 3);
                            const h2 p2 = __builtin_shufflevector(v, v, 4, 5);
                            const h2 p3 = __builtin_shufflevector(v, v, 6, 7);
                            c0 = dot2(p0, bwA[4 * r + 0], c0);
                            c1 = dot2(p1, bwA[4 * r + 1], c1);
                            c2 = dot2(p2, bwA[4 * r + 2], c2);
                            c3 = dot2(p3, bwA[4 * r + 3], c3);
                        }
                        float part = (c0 + c1) + (c2 + c3);
                        if (khA) part += pcA[ph];
                        apar[khA][colA] = part;
                    }
                    __syncthreads();

                    if (tid < Hn) {
                        const float yU = yv + ypU[tid] + pcU[ph];
                        const float yA = apar[0][tid] + apar[1][tid];
                        const float cand  = fast_tanh(yU);
                        const float alpha = fast_sigmoid(yA);
                        const float hn = hprev + alpha * (cand - hprev);
                        hprev = hn;
                        hst[ph] = hn;
                        hbuf[(t + 1) & 1][tid] = (_Float16)hn;
                    }
                    __syncthreads();
                }

                if (tid < Hn) {
                    #pragma unroll
                    for (int k = 0; k < 8; ++k)
                        outb[(size_t)(t0 + k) * Hn + tid] = hst[k];
                }
            }
        }

        if (tid < Hn) hfin[Bn * Hn + b * Hn + tid] = hprev;
    }
}

extern "C" void kernel_launch(void* const* d_in, const int* in_sizes, int n_in,
                              void* d_out, int out_size, void* d_ws, size_t ws_size,
                              hipStream_t stream) {
    const float* X    = (const float*)d_in[0];
    const float* Wih0 = (const float*)d_in[1];
    const float* Whh0 = (const float*)d_in[2];
    const float* bh0  = (const float*)d_in[3];
    const float* Wax0 = (const float*)d_in[4];
    const float* Wah0 = (const float*)d_in[5];
    const float* ba0  = (const float*)d_in[6];
    const float* Wih1 = (const float*)d_in[7];
    const float* Whh1 = (const float*)d_in[8];
    const float* bh1  = (const float*)d_in[9];
    const float* Wax1 = (const float*)d_in[10];
    const float* Wah1 = (const float*)d_in[11];
    const float* ba1  = (const float*)d_in[12];

    float* outf = (float*)d_out;
    float* hfin = outf + (size_t)Bn * Tn * Hn;
    _Float16* pre = (_Float16*)d_out;
    int* prog = (int*)d_ws;

    hipMemsetAsync(prog, 0, Bn * sizeof(int), stream);
    gemm_x_kernel<<<dim3((Bn * Tn) / 64, 2), 256, 0, stream>>>(X, Wih0, bh0, Wax0, ba0, pre);
    fused_scan<<<dim3(2 * Bn), 1024, 0, stream>>>(pre, Whh0, Wah0,
                                                  Wih1, Wax1, bh1, ba1,
                                                  Whh1, Wah1, outf, hfin, prog);
}

// Round 13
// 3113.230 us; speedup vs baseline: 3.1319x; 3.1319x over previous
//
#include <hip/hip_runtime.h>

#define Bn 64
#define Tn 2048
#define In 128
#define Hn 256
#define RS 512  // row stride in f16 elements for pre/out rows (1024 B)

#define H0S (Hn + 8)       // h0t row stride (f16 elems)
#define PLS (2 * Hn + 8)   // preL row stride (f16 elems)
#define GC  8              // chunks per pipeline group (64 steps)

typedef _Float16 h2 __attribute__((ext_vector_type(2)));
typedef _Float16 f16x8 __attribute__((ext_vector_type(8)));
typedef float f32x4 __attribute__((ext_vector_type(4)));

__device__ __forceinline__ float fast_sigmoid(float x) {
    return 1.0f / (1.0f + __expf(-x));
}
__device__ __forceinline__ float fast_tanh(float x) {
    return 2.0f / (1.0f + __expf(-2.0f * x)) - 1.0f;
}
__device__ __forceinline__ h2 bc2(float f) {
    return __builtin_bit_cast(h2, f);
}

#if __has_builtin(__builtin_amdgcn_fdot2)
__device__ __forceinline__ float dot2(h2 a, h2 b, float c) {
    return __builtin_amdgcn_fdot2(a, b, c, false);
}
#else
__device__ __forceinline__ float dot2(h2 a, h2 b, float c) {
    return c + (float)a.x * (float)b.x + (float)a.y * (float)b.y;
}
#endif

// ---------------------------------------------------------------------------
// K1: pre0[m][512] (f16, in d_out) = X[m][0:128] @ [Wih0 | Wax0] + [bh0 | ba0]
// ---------------------------------------------------------------------------
__global__ void gemm_x_kernel(const float* __restrict__ X,
                              const float* __restrict__ Wih0, const float* __restrict__ bh0,
                              const float* __restrict__ Wax0, const float* __restrict__ ba0,
                              _Float16* __restrict__ pre)
{
    __shared__ __align__(16) float Xs[64 * In];  // 32 KB
    const int m0 = blockIdx.x * 64;
    const int s  = blockIdx.y;
    const float* __restrict__ W    = s ? Wax0 : Wih0;
    const float* __restrict__ bias = s ? ba0  : bh0;

    {
        const float4* __restrict__ src = reinterpret_cast<const float4*>(X + (size_t)m0 * In);
        float4* __restrict__ dst = reinterpret_cast<float4*>(Xs);
        #pragma unroll
        for (int i = 0; i < 8; ++i) dst[threadIdx.x + 256 * i] = src[threadIdx.x + 256 * i];
    }
    __syncthreads();

    const int c  = threadIdx.x & 63;
    const int rg = threadIdx.x >> 6;
    const int mr = rg * 16;

    float acc[16][4];
    #pragma unroll
    for (int u = 0; u < 4; ++u) {
        const float bv = bias[c + 64 * u];
        #pragma unroll
        for (int r = 0; r < 16; ++r) acc[r][u] = bv;
    }

    const float4* __restrict__ Xs4 = reinterpret_cast<const float4*>(Xs);
    #pragma unroll 4
    for (int kc = 0; kc < 32; ++kc) {
        float wv[4][4];
        #pragma unroll
        for (int kk = 0; kk < 4; ++kk)
            #pragma unroll
            for (int u = 0; u < 4; ++u)
                wv[kk][u] = W[(size_t)(4 * kc + kk) * Hn + c + 64 * u];
        #pragma unroll
        for (int r = 0; r < 16; ++r) {
            const float4 xv = Xs4[(mr + r) * 32 + kc];
            #pragma unroll
            for (int u = 0; u < 4; ++u)
                acc[r][u] += xv.x * wv[0][u] + xv.y * wv[1][u] + xv.z * wv[2][u] + xv.w * wv[3][u];
        }
    }

    #pragma unroll
    for (int r = 0; r < 16; ++r)
        #pragma unroll
        for (int u = 0; u < 4; ++u)
            pre[(size_t)(m0 + mr + r) * RS + s * Hn + c + 64 * u] = (_Float16)acc[r][u];
}

// ---------------------------------------------------------------------------
// Fused two-layer scan (R11 structure restored), with:
//  - GROUPS OF 8 CHUNKS (64 steps): half the fences of R11, amortized prep.
//  - Consumer preL reads HOISTED into registers per chunk and folded
//    producer-style (kq=0 holds pcU, kq=1 holds pcA pre-barrier), so the
//    consumer's scan step is instruction-identical to the producer's.
// R12's hybrid is reverted: divergent per-role weight arrays double the
// worst-case register demand and spilled to scratch (FETCH 125->676 MB).
// ---------------------------------------------------------------------------
__global__ __launch_bounds__(1024, 4)
void fused_scan(_Float16* __restrict__ pre,
                const float* __restrict__ WU0, const float* __restrict__ WA0,
                const float* __restrict__ Wih1, const float* __restrict__ Wax1,
                const float* __restrict__ bh1,  const float* __restrict__ ba1,
                const float* __restrict__ WU1,  const float* __restrict__ WA1,
                float* __restrict__ outf, float* __restrict__ hfin,
                int* __restrict__ prog)
{
    __shared__ __align__(16) _Float16 hbuf[2][Hn];      // 1 KB
    __shared__ __align__(16) float2   pbuf[3][Hn];      // 6 KB
    __shared__ __align__(16) _Float16 h0t[8 * GC][H0S]; // 33.8 KB
    __shared__ __align__(16) _Float16 preL[8 * GC][PLS];// 66.6 KB

    const int tid  = threadIdx.x;
    const int col  = tid & 255;
    const int kq   = tid >> 8;
    const int lane = tid & 63;
    const int w    = tid >> 6;
    const int g    = lane >> 4;
    const int cl   = lane & 15;

    if (blockIdx.x < Bn) {
        // ========================= layer 0 (producer) =========================
        const int b = blockIdx.x;
        h2 bwU[32], bwA[32];
        #pragma unroll
        for (int i = 0; i < 32; ++i) {
            const int k0 = 64 * kq + 2 * i;
            h2 u, a;
            u.x = (_Float16)WU0[(size_t)k0 * Hn + col];
            u.y = (_Float16)WU0[(size_t)(k0 + 1) * Hn + col];
            a.x = (_Float16)WA0[(size_t)k0 * Hn + col];
            a.y = (_Float16)WA0[(size_t)(k0 + 1) * Hn + col];
            bwU[i] = u;
            bwA[i] = a;
        }

        _Float16* __restrict__ rowbase = pre + (size_t)b * Tn * RS;
        float hprev = 0.0f;

        if (tid < Hn) hbuf[0][tid] = (_Float16)0.0f;
        float pc[8];
        if (kq < 2) {
            const int off = kq ? Hn : 0;
            #pragma unroll
            for (int k = 0; k < 8; ++k)
                pc[k] = (float)rowbase[(size_t)k * RS + off + col];
        }
        __syncthreads();

        for (int t0 = 0; t0 < Tn; t0 += 8) {
            float pn[8];
            if (kq < 2) {
                const int off = kq ? Hn : 0;
                #pragma unroll
                for (int k = 0; k < 8; ++k) {
                    int tn = t0 + 8 + k;
                    if (tn > Tn - 1) tn = Tn - 1;
                    pn[k] = (float)rowbase[(size_t)tn * RS + off + col];
                }
            }

            float hst[8];

            #pragma unroll
            for (int ph = 0; ph < 8; ++ph) {
                const int t = t0 + ph;
                const f16x8* __restrict__ hb =
                    reinterpret_cast<const f16x8*>(&hbuf[t & 1][64 * kq]);

                float aU[2] = {0.0f, 0.0f};
                float aA[2] = {0.0f, 0.0f};
                #pragma unroll
                for (int r = 0; r < 8; ++r) {
                    const f16x8 v = hb[r];
                    const h2 p0 = __builtin_shufflevector(v, v, 0, 1);
                    const h2 p1 = __builtin_shufflevector(v, v, 2, 3);
                    const h2 p2 = __builtin_shufflevector(v, v, 4, 5);
                    const h2 p3 = __builtin_shufflevector(v, v, 6, 7);
                    aU[0] = dot2(p0, bwU[4 * r + 0], aU[0]);
                    aU[1] = dot2(p1, bwU[4 * r + 1], aU[1]);
                    aU[0] = dot2(p2, bwU[4 * r + 2], aU[0]);
                    aU[1] = dot2(p3, bwU[4 * r + 3], aU[1]);
                    aA[0] = dot2(p0, bwA[4 * r + 0], aA[0]);
                    aA[1] = dot2(p1, bwA[4 * r + 1], aA[1]);
                    aA[0] = dot2(p2, bwA[4 * r + 2], aA[0]);
                    aA[1] = dot2(p3, bwA[4 * r + 3], aA[1]);
                }
                float partU = aU[0] + aU[1];
                float partA = aA[0] + aA[1];
                if (kq == 1) partA += pc[ph];

                if (kq) pbuf[kq - 1][col] = make_float2(partU, partA);
                __syncthreads();

                if (kq == 0) {
                    const float2 q0 = pbuf[0][col];
                    const float2 q1 = pbuf[1][col];
                    const float2 q2 = pbuf[2][col];
                    const float yU = partU + q0.x + q1.x + q2.x + pc[ph];
                    const float yA = partA + q0.y + q1.y + q2.y;
                    const float cand  = fast_tanh(yU);
                    const float alpha = fast_sigmoid(yA);
                    const float hn = hprev + alpha * (cand - hprev);
                    hprev = hn;
                    hst[ph] = hn;
                    hbuf[(t + 1) & 1][col] = (_Float16)hn;
                }
                __syncthreads();
            }

            // chunk flush: h0 rows -> global (f16, U-half of pre0 rows)
            if (kq == 0) {
                #pragma unroll
                for (int k = 0; k < 8; ++k)
                    rowbase[(size_t)(t0 + k) * RS + col] = (_Float16)hst[k];
            }
            if (kq < 2) {
                #pragma unroll
                for (int k = 0; k < 8; ++k) pc[k] = pn[k];
            }

            // group boundary (every GC-th chunk): drain, ONE fence, release
            if (((t0 >> 3) & (GC - 1)) == (GC - 1)) {
                __syncthreads();
                if (tid == 0) {
                    __threadfence();
                    __hip_atomic_store(prog + b, (t0 >> 3) / GC + 1,
                                       __ATOMIC_RELEASE, __HIP_MEMORY_SCOPE_AGENT);
                }
            }
        }

        if (kq == 0) hfin[b * Hn + col] = hprev;

    } else {
        // ========================= layer 1 (consumer) =========================
        const int b = blockIdx.x - Bn;

        // mini-GEMM B fragments (persistent; used once per group)
        f16x8 bfr0[8], bfr1[8];
        float biasv0, biasv1;
        int cg0, cg1;
        {
            const int ntgA = 2 * w, ntgB = 2 * w + 1;
            const float* __restrict__ WmA = (ntgA < 16) ? Wih1 : Wax1;
            const float* __restrict__ WmB = (ntgB < 16) ? Wih1 : Wax1;
            const int nA = 16 * (ntgA & 15) + cl;
            const int nB = 16 * (ntgB & 15) + cl;
            biasv0 = (ntgA < 16) ? bh1[nA] : ba1[nA];
            biasv1 = (ntgB < 16) ? bh1[nB] : ba1[nB];
            cg0 = (ntgA < 16) ? nA : (Hn + nA);
            cg1 = (ntgB < 16) ? nB : (Hn + nB);
            #pragma unroll
            for (int kc = 0; kc < 8; ++kc) {
                const int k0 = 32 * kc + 8 * g;
                f16x8 fa, fb;
                #pragma unroll
                for (int jj = 0; jj < 8; ++jj) {
                    fa[jj] = (_Float16)WmA[(size_t)(k0 + jj) * Hn + nA];
                    fb[jj] = (_Float16)WmB[(size_t)(k0 + jj) * Hn + nB];
                }
                bfr0[kc] = fa;
                bfr1[kc] = fb;
            }
        }

        // scan weights (Whh1 / Wah1), K-split layout
        h2 bwU[32], bwA[32];
        #pragma unroll
        for (int i = 0; i < 32; ++i) {
            const int k0 = 64 * kq + 2 * i;
            h2 u, a;
            u.x = (_Float16)WU1[(size_t)k0 * Hn + col];
            u.y = (_Float16)WU1[(size_t)(k0 + 1) * Hn + col];
            a.x = (_Float16)WA1[(size_t)k0 * Hn + col];
            a.y = (_Float16)WA1[(size_t)(k0 + 1) * Hn + col];
            bwU[i] = u;
            bwA[i] = a;
        }

        _Float16* __restrict__ rowbase = pre + (size_t)b * Tn * RS;
        float* __restrict__ outb = outf + (size_t)b * Tn * Hn;
        float hprev = 0.0f;

        if (tid < Hn) hbuf[0][tid] = (_Float16)0.0f;
        __syncthreads();

        for (int grp = 0; grp < Tn / (8 * GC); ++grp) {
            const int t0g = 8 * GC * grp;

            // acquire group: relaxed poll, single acquire load
            if (tid == 0) {
                while (__hip_atomic_load(prog + b, __ATOMIC_RELAXED,
                                         __HIP_MEMORY_SCOPE_AGENT) <= grp)
                    __builtin_amdgcn_s_sleep(8);
                (void)__hip_atomic_load(prog + b, __ATOMIC_ACQUIRE,
                                        __HIP_MEMORY_SCOPE_AGENT);
            }
            __syncthreads();

            // 8*GC h0 rows -> LDS
            #pragma unroll
            for (int qq = 0; qq < GC; ++qq) {
                const int id  = tid + 1024 * qq;
                const int r   = id >> 7;
                const int off = id & 127;
                const unsigned int v = *reinterpret_cast<const unsigned int*>(
                    rowbase + (size_t)(t0g + r) * RS + 2 * off);
                *reinterpret_cast<unsigned int*>(&h0t[r][2 * off]) = v;
            }
            __syncthreads();

            // M=8*GC mini-GEMM -> preL
            #pragma unroll
            for (int mt = 0; mt < GC / 2; ++mt) {
                f16x8 af[8];
                #pragma unroll
                for (int kc = 0; kc < 8; ++kc)
                    af[kc] = *reinterpret_cast<const f16x8*>(
                        &h0t[16 * mt + cl][32 * kc + 8 * g]);

                const f32x4 z = {0.0f, 0.0f, 0.0f, 0.0f};
                f32x4 a0 = __builtin_amdgcn_mfma_f32_16x16x32_f16(af[0], bfr0[0], z, 0, 0, 0);
                f32x4 a1 = __builtin_amdgcn_mfma_f32_16x16x32_f16(af[0], bfr1[0], z, 0, 0, 0);
                #pragma unroll
                for (int kc = 1; kc < 8; ++kc) {
                    a0 = __builtin_amdgcn_mfma_f32_16x16x32_f16(af[kc], bfr0[kc], a0, 0, 0, 0);
                    a1 = __builtin_amdgcn_mfma_f32_16x16x32_f16(af[kc], bfr1[kc], a1, 0, 0, 0);
                }
                const int r0 = 16 * mt + (lane >> 4) * 4;
                #pragma unroll
                for (int ri = 0; ri < 4; ++ri) {
                    preL[r0 + ri][cg0] = (_Float16)(a0[ri] + biasv0);
                    preL[r0 + ri][cg1] = (_Float16)(a1[ri] + biasv1);
                }
            }
            __syncthreads();

            for (int cc = 0; cc < GC; ++cc) {
                const int t0 = t0g + 8 * cc;

                // HOISTED pre reads from preL (producer-mirror: kq=0 pU, kq=1 pA)
                float pc[8];
                if (kq < 2) {
                    const int off = kq ? Hn : 0;
                    #pragma unroll
                    for (int ph = 0; ph < 8; ++ph)
                        pc[ph] = (float)preL[8 * cc + ph][off + col];
                }

                float hst[8];
                #pragma unroll
                for (int ph = 0; ph < 8; ++ph) {
                    const int t = t0 + ph;
                    const f16x8* __restrict__ hb =
                        reinterpret_cast<const f16x8*>(&hbuf[t & 1][64 * kq]);

                    float aU[2] = {0.0f, 0.0f};
                    float aA[2] = {0.0f, 0.0f};
                    #pragma unroll
                    for (int r = 0; r < 8; ++r) {
                        const f16x8 v = hb[r];
                        const h2 p0 = __builtin_shufflevector(v, v, 0, 1);
                        const h2 p1 = __builtin_shufflevector(v, v, 2, 3);
                        const h2 p2 = __builtin_shufflevector(v, v, 4, 5);
                        const h2 p3 = __builtin_shufflevector(v, v, 6, 7);
                        aU[0] = dot2(p0, bwU[4 * r + 0], aU[0]);
                        aU[1] = dot2(p1, bwU[4 * r + 1], aU[1]);
                        aU[0] = dot2(p2, bwU[4 * r + 2], aU[0]);
                        aU[1] = dot2(p3, bwU[4 * r + 3], aU[1]);
                        aA[0] = dot2(p0, bwA[4 * r + 0], aA[0]);
                        aA[1] = dot2(p1, bwA[4 * r + 1], aA[1]);
                        aA[0] = dot2(p2, bwA[4 * r + 2], aA[0]);
                        aA[1] = dot2(p3, bwA[4 * r + 3], aA[1]);
                    }
                    float partU = aU[0] + aU[1];
                    float partA = aA[0] + aA[1];
                    if (kq == 1) partA += pc[ph];

                    if (kq) pbuf[kq - 1][col] = make_float2(partU, partA);
                    __syncthreads();

                    if (kq == 0) {
                        const float2 q0 = pbuf[0][col];
                        const float2 q1 = pbuf[1][col];
                        const float2 q2 = pbuf[2][col];
                        const float yU = partU + q0.x + q1.x + q2.x + pc[ph];
                        const float yA = partA + q0.y + q1.y + q2.y;
                        const float cand  = fast_tanh(yU);
                        const float alpha = fast_sigmoid(yA);
                        const float hn = hprev + alpha * (cand - hprev);
                        hprev = hn;
                        hst[ph] = hn;
                        hbuf[(t + 1) & 1][col] = (_Float16)hn;
                    }
                    __syncthreads();
                }

                // chunk flush: outputs f32 (overwrites consumed pre0 bytes)
                if (kq == 0) {
                    #pragma unroll
                    for (int k = 0; k < 8; ++k)
                        outb[(size_t)(t0 + k) * Hn + col] = hst[k];
                }
            }
        }

        if (kq == 0) hfin[Bn * Hn + b * Hn + col] = hprev;
    }
}

extern "C" void kernel_launch(void* const* d_in, const int* in_sizes, int n_in,
                              void* d_out, int out_size, void* d_ws, size_t ws_size,
                              hipStream_t stream) {
    const float* X    = (const float*)d_in[0];
    const float* Wih0 = (const float*)d_in[1];
    const float* Whh0 = (const float*)d_in[2];
    const float* bh0  = (const float*)d_in[3];
    const float* Wax0 = (const float*)d_in[4];
    const float* Wah0 = (const float*)d_in[5];
    const float* ba0  = (const float*)d_in[6];
    const float* Wih1 = (const float*)d_in[7];
    const float* Whh1 = (const float*)d_in[8];
    const float* bh1  = (const float*)d_in[9];
    const float* Wax1 = (const float*)d_in[10];
    const float* Wah1 = (const float*)d_in[11];
    const float* ba1  = (const float*)d_in[12];

    float* outf = (float*)d_out;
    float* hfin = outf + (size_t)Bn * Tn * Hn;
    _Float16* pre = (_Float16*)d_out;
    int* prog = (int*)d_ws;

    hipMemsetAsync(prog, 0, Bn * sizeof(int), stream);
    gemm_x_kernel<<<dim3((Bn * Tn) / 64, 2), 256, 0, stream>>>(X, Wih0, bh0, Wax0, ba0, pre);
    fused_scan<<<dim3(2 * Bn), 1024, 0, stream>>>(pre, Whh0, Wah0,
                                                  Wih1, Wax1, bh1, ba1,
                                                  Whh1, Wah1, outf, hfin, prog);
}